// Round 4
// baseline (513.741 us; speedup 1.0000x reference)
//
#include <hip/hip_runtime.h>
#include <hip/hip_bf16.h>

#define EPS 1e-5f
#define CAP 6144     // slots per 256-node bucket (expected 4092 edges, 32-sigma slack)
#define PCHUNK 4096

// accumulate 8 bf16 features from one uint4 (lo/hi of each dword)
__device__ __forceinline__ void acc_bf(float* acc, uint4 v) {
    acc[0] += __uint_as_float(v.x << 16);
    acc[1] += __uint_as_float(v.x & 0xffff0000u);
    acc[2] += __uint_as_float(v.y << 16);
    acc[3] += __uint_as_float(v.y & 0xffff0000u);
    acc[4] += __uint_as_float(v.z << 16);
    acc[5] += __uint_as_float(v.z & 0xffff0000u);
    acc[6] += __uint_as_float(v.w << 16);
    acc[7] += __uint_as_float(v.w & 0xffff0000u);
}

__device__ __forceinline__ unsigned bf16rne(float f) {
    unsigned u = __float_as_uint(f);
    return (u + 0x7fffu + ((u >> 16) & 1u)) >> 16;
}
__device__ __forceinline__ unsigned pack2bf(float a, float b) {
    return bf16rne(a) | (bf16rne(b) << 16);
}

// ---------------- init: bucket cursors + zero stats ----------------
__global__ void k_init(int* __restrict__ cur, float* __restrict__ stats) {
    int t = threadIdx.x;  // 512
    stats[t] = 0.0f;
    cur[t] = t * CAP;
}

// ------- fused: blocks [0,NBP) fixed-cap partition; blocks [NBP,NBP+512) colstats x -------
__global__ __launch_bounds__(256) void k_A(
    const int* __restrict__ src, const int* __restrict__ dst,
    int* __restrict__ cur, unsigned* __restrict__ packbuf, int E, int NBP,
    const float* __restrict__ x, float* __restrict__ xsum, float* __restrict__ xsq, int N) {
    __shared__ int h[512], delta[512], wsc[4];
    __shared__ unsigned buf[PCHUNK];
    __shared__ int addr[PCHUNK];
    int tx = threadIdx.x;
    if ((int)blockIdx.x < NBP) {
        int e0 = blockIdx.x * PCHUNK;
        int e1 = min(e0 + PCHUNK, E);
        int csize = e1 - e0;
        h[tx] = 0; h[tx + 256] = 0;
        __syncthreads();
        // phase 1: histogram of dst>>8 within chunk
        for (int e = e0 + tx; e < e1; e += 256)
            atomicAdd(&h[dst[e] >> 8], 1);
        __syncthreads();
        // phase 2: exclusive scan (2 entries/thread, regs + shfl)
        int b0 = tx * 2;
        int c0 = h[b0], c1 = h[b0 + 1];
        int tsum = c0 + c1;
        int lane = tx & 63, wid = tx >> 6;
        int v = tsum;
#pragma unroll
        for (int off = 1; off < 64; off <<= 1) {
            int u = __shfl_up(v, off);
            if (lane >= off) v += u;
        }
        if (lane == 63) wsc[wid] = v;
        __syncthreads();
        int wbase = 0;
        for (int w = 0; w < wid; w++) wbase += wsc[w];
        int excl0 = wbase + v - tsum;
        int excl1 = excl0 + c0;
        // claim bucket space directly (cursors pre-seeded at b*CAP)
        if (c0 > 0) delta[b0] = atomicAdd(&cur[b0], c0) - excl0;
        if (c1 > 0) delta[b0 + 1] = atomicAdd(&cur[b0 + 1], c1) - excl1;
        __syncthreads();
        h[b0] = excl0; h[b0 + 1] = excl1;
        __syncthreads();
        // phase 3: LDS scatter into bucket-sorted order, recording write delta
        for (int e = e0 + tx; e < e1; e += 256) {
            int d = dst[e];
            int b = d >> 8;
            int rank = atomicAdd(&h[b], 1);
            buf[rank] = ((unsigned)src[e] << 8) | (unsigned)(d & 255);
            addr[rank] = delta[b];
        }
        __syncthreads();
        // phase 4: coalesced write-out
        for (int i = tx; i < csize; i += 256)
            packbuf[addr[i] + i] = buf[i];
    } else {
        float* ls = (float*)buf;
        float* lq = ls + 256;
        int b2 = blockIdx.x - NBP;  // 0..511
        int col = tx & 127, half = tx >> 7;
        float s = 0.f, q = 0.f;
        for (int r = b2 * 2 + half; r < N; r += 1024) {
            float v = x[(long long)r * 128 + col];
            s += v; q += v * v;
        }
        ls[tx] = s; lq[tx] = q;
        __syncthreads();
        if (half == 0) {
            s = ls[tx] + ls[tx + 128];
            q = lq[tx] + lq[tx + 128];
            atomicAdd(&xsum[col], s);
            atomicAdd(&xsq[col], q);
        }
    }
}

// ------- fused: blocks [0,NB) CSR build (src-half segmented); blocks [NB,..) gemm1 -------
__global__ __launch_bounds__(512) void k_B(
    const unsigned* __restrict__ packbuf, const int* __restrict__ cur,
    int2* __restrict__ rowbe, int* __restrict__ rowmid, float* __restrict__ dinv,
    int* __restrict__ eidx, int NB, int N, int Nh,
    const float* __restrict__ x, const float* __restrict__ stats,
    const float* __restrict__ g, const float* __restrict__ bbn,
    const float* __restrict__ Wp, const float* __restrict__ bp,
    float* __restrict__ H, float invN) {
    __shared__ int cnt[512], loff[512], wsum[8];
    int tx = threadIdx.x;  // 512
    if ((int)blockIdx.x < NB) {
        int b = blockIdx.x;
        int base = b * CAP;
        int end = cur[b];
        cnt[tx] = 0;
        __syncthreads();
        // histogram over key = (local_node<<1) | src_half
        for (int e = base + tx; e < end; e += 512) {
            unsigned pk = packbuf[e];
            int key = (((int)pk & 255) << 1) | (int)((pk >> 8) >= (unsigned)Nh);
            atomicAdd(&cnt[key], 1);
        }
        __syncthreads();
        // exclusive scan over 512 keys (1/thread, shfl + wave sums)
        int c = cnt[tx];
        int lane = tx & 63, wid = tx >> 6;
        int v = c;
#pragma unroll
        for (int off = 1; off < 64; off <<= 1) {
            int u = __shfl_up(v, off);
            if (lane >= off) v += u;
        }
        if (lane == 63) wsum[wid] = v;
        __syncthreads();
        int wbase = 0;
        for (int w = 0; w < wid; w++) wbase += wsum[w];
        int excl = wbase + v - c;
        loff[tx] = excl;
        __syncthreads();
        // per-node row pointers (read loff/cnt before scatter mutates loff)
        if (tx < 256) {
            int node = b * 256 + tx;
            if (node < N) {
                int beg = base + loff[2 * tx];
                int mid = base + loff[2 * tx + 1];
                int e2 = mid + cnt[2 * tx + 1];
                rowbe[node] = make_int2(beg, e2);
                rowmid[node] = mid;
                int deg = cnt[2 * tx] + cnt[2 * tx + 1];
                dinv[node] = rsqrtf(1.0f + (float)deg);
            }
        }
        __syncthreads();
        // scatter into segmented order
        for (int e = base + tx; e < end; e += 512) {
            unsigned pk = packbuf[e];
            int key = (((int)pk & 255) << 1) | (int)((pk >> 8) >= (unsigned)Nh);
            int pos = atomicAdd(&loff[key], 1);
            eidx[base + pos] = (int)(pk >> 8);
        }
    } else {
        float* sc = (float*)cnt;   // 128
        float* sh = (float*)loff;  // 128
        if (tx < 128) {
            float mu = stats[tx] * invN;
            float var = stats[128 + tx] * invN - mu * mu;
            float s = g[tx] * rsqrtf(var + EPS);
            sc[tx] = s;
            sh[tx] = bbn[tx] - mu * s;
        }
        __syncthreads();
        int r = ((int)blockIdx.x - NB) * 512 + tx;
        if (r >= N) return;
        float acc[64];
#pragma unroll
        for (int j = 0; j < 64; j++) acc[j] = 0.f;
        const float4* x4 = (const float4*)(x + (long long)r * 128);
        for (int c4 = 0; c4 < 32; c4++) {
            float4 xv = x4[c4];
            int cb = c4 * 4;
            xv.x = xv.x * sc[cb + 0] + sh[cb + 0];
            xv.y = xv.y * sc[cb + 1] + sh[cb + 1];
            xv.z = xv.z * sc[cb + 2] + sh[cb + 2];
            xv.w = xv.w * sc[cb + 3] + sh[cb + 3];
#pragma unroll
            for (int q = 0; q < 4; q++) {
                float xs = (q == 0) ? xv.x : (q == 1) ? xv.y : (q == 2) ? xv.z : xv.w;
                const float* wrow = Wp + (c4 * 4 + q) * 64;
#pragma unroll
                for (int j = 0; j < 64; j++) acc[j] += xs * wrow[j];
            }
        }
        float4* out4 = (float4*)(H + (long long)r * 64);
#pragma unroll
        for (int i = 0; i < 16; i++) {
            float4 vv;
            vv.x = fmaxf(acc[4 * i + 0] + bp[4 * i + 0], 0.f);
            vv.y = fmaxf(acc[4 * i + 1] + bp[4 * i + 1], 0.f);
            vv.z = fmaxf(acc[4 * i + 2] + bp[4 * i + 2], 0.f);
            vv.w = fmaxf(acc[4 * i + 3] + bp[4 * i + 3], 0.f);
            out4[i] = vv;
        }
    }
}

// ------- gemm_rows: hr = (optional BN+relu(In)) @ W * dinv[row] -> bf16 rows (128 B) -------
template <bool BNRELU>
__global__ __launch_bounds__(256) void k_gemm_rows(
    const float* __restrict__ In, const float* __restrict__ W,
    const float* __restrict__ dinv, const float* __restrict__ ssum,
    const float* __restrict__ ssq, const float* __restrict__ g,
    const float* __restrict__ bb, float invN, unsigned* __restrict__ Hq, int N) {
    __shared__ float scs[64], shs[64];
    int tx = threadIdx.x;
    if (BNRELU) {
        if (tx < 64) {
            float mu = ssum[tx] * invN;
            float var = ssq[tx] * invN - mu * mu;
            float s = g[tx] * rsqrtf(var + EPS);
            scs[tx] = s;
            shs[tx] = bb[tx] - mu * s;
        }
        __syncthreads();
    }
    int r = blockIdx.x * blockDim.x + tx;
    if (r >= N) return;
    float acc[64];
#pragma unroll
    for (int j = 0; j < 64; j++) acc[j] = 0.f;
    const float4* in4 = (const float4*)(In + (long long)r * 64);
    for (int c4 = 0; c4 < 16; c4++) {
        float4 xv = in4[c4];
        if (BNRELU) {
            int cb = c4 * 4;
            xv.x = fmaxf(xv.x * scs[cb + 0] + shs[cb + 0], 0.f);
            xv.y = fmaxf(xv.y * scs[cb + 1] + shs[cb + 1], 0.f);
            xv.z = fmaxf(xv.z * scs[cb + 2] + shs[cb + 2], 0.f);
            xv.w = fmaxf(xv.w * scs[cb + 3] + shs[cb + 3], 0.f);
        }
#pragma unroll
        for (int q = 0; q < 4; q++) {
            float xs = (q == 0) ? xv.x : (q == 1) ? xv.y : (q == 2) ? xv.z : xv.w;
            const float* wrow = W + (c4 * 4 + q) * 64;
#pragma unroll
            for (int j = 0; j < 64; j++) acc[j] += xs * wrow[j];
        }
    }
    float dv = dinv[r];
#pragma unroll
    for (int j = 0; j < 64; j++) acc[j] *= dv;
    uint4* hr = (uint4*)(Hq + (long long)r * 32);
#pragma unroll
    for (int i = 0; i < 8; i++) {
        uint4 u;
        u.x = pack2bf(acc[8 * i + 0], acc[8 * i + 1]);
        u.y = pack2bf(acc[8 * i + 2], acc[8 * i + 3]);
        u.z = pack2bf(acc[8 * i + 4], acc[8 * i + 5]);
        u.w = pack2bf(acc[8 * i + 6], acc[8 * i + 7]);
        hr[i] = u;
    }
    // zero dummy row N (tail lanes in the gather point here)
    if (r == 0) {
        uint4 z = make_uint4(0u, 0u, 0u, 0u);
        uint4* zr = (uint4*)(Hq + (long long)N * 32);
#pragma unroll
        for (int i = 0; i < 8; i++) zr[i] = z;
    }
}

// ------- gather+finish: out[d] = dinv[d]*(hr[d] + sum_nbr hr[s]) + b; stats -------
// 8 lanes per node (each lane owns one uint4 = 8 bf16 feats), 32 nodes per 256-block.
// One 128-B line per edge, no scale table. MLP-8 chunks with idx prefetch; src-half
// segmented order retained from the CSR build.
__global__ __launch_bounds__(256) void k_gather_finish(
    const uint4* __restrict__ B, const int2* __restrict__ rowbe,
    const int* __restrict__ rowmid, const int* __restrict__ eidx,
    const float* __restrict__ dinv, const float* __restrict__ bias,
    float* __restrict__ Out, float* __restrict__ ssum, float* __restrict__ ssq,
    int N) {
    int tx = threadIdx.x;
    int g = tx >> 3;   // node slot in block (32 per block)
    int l = tx & 7;    // feature octet
    int d = blockIdx.x * 32 + g;

    float s[8], q[8];
#pragma unroll
    for (int j = 0; j < 8; j++) { s[j] = 0.f; q[j] = 0.f; }

    if (d < N) {
        int2 be = rowbe[d];
        int mid = rowmid[d];
        // self term + row constants issued first
        uint4 v0 = B[(long long)d * 8 + l];
        float dv = dinv[d];

        float acc[8];
#pragma unroll
        for (int j = 0; j < 8; j++) acc[j] = 0.f;

        for (int seg = 0; seg < 2; seg++) {
            int k  = seg ? mid : be.x;
            int ke = seg ? be.y : mid;
            if (k >= ke) continue;
            int idx_cur[8];
#pragma unroll
            for (int j = 0; j < 8; j++)
                idx_cur[j] = (k + j < ke) ? eidx[k + j] : N;   // row N is zero

            while (k < ke) {
                uint4 bb[8];
#pragma unroll
                for (int j = 0; j < 8; j++)
                    bb[j] = B[(long long)idx_cur[j] * 8 + l];
                int kn = k + 8;
                int idx_nxt[8];
#pragma unroll
                for (int j = 0; j < 8; j++)
                    idx_nxt[j] = (kn + j < ke) ? eidx[kn + j] : N;
#pragma unroll
                for (int j = 0; j < 8; j++)
                    acc_bf(acc, bb[j]);
#pragma unroll
                for (int j = 0; j < 8; j++) idx_cur[j] = idx_nxt[j];
                k = kn;
            }
        }
        // self term
        acc_bf(acc, v0);

        float4 o0, o1;
#pragma unroll
        for (int j = 0; j < 8; j++) {
            float v = acc[j] * dv + bias[8 * l + j];
            ((j < 4) ? (&o0.x)[j] : (&o1.x)[j - 4]) = v;
            s[j] += v; q[j] += v * v;
        }
        float4* outp = (float4*)(Out + (long long)d * 64 + 8 * l);
        outp[0] = o0;
        outp[1] = o1;
    }

#pragma unroll
    for (int m = 8; m <= 32; m <<= 1) {
#pragma unroll
        for (int j = 0; j < 8; j++) {
            s[j] += __shfl_xor(s[j], m, 64);
            q[j] += __shfl_xor(q[j], m, 64);
        }
    }
    __shared__ float ws_s[4][64], ws_q[4][64];
    int wv = tx >> 6, ln = tx & 63;
    if (ln < 8) {
#pragma unroll
        for (int j = 0; j < 8; j++) {
            ws_s[wv][ln * 8 + j] = s[j];
            ws_q[wv][ln * 8 + j] = q[j];
        }
    }
    __syncthreads();
    if (tx < 64) {
        float S2 = ws_s[0][tx] + ws_s[1][tx] + ws_s[2][tx] + ws_s[3][tx];
        float Q2 = ws_q[0][tx] + ws_q[1][tx] + ws_q[2][tx] + ws_q[3][tx];
        atomicAdd(&ssum[tx], S2);
        atomicAdd(&ssq[tx], Q2);
    }
}

// ---------------- final elementwise BN apply (stats inline, in-place safe) ----------------
__global__ __launch_bounds__(256) void k_final(const float* __restrict__ In,
                                               const float* __restrict__ ssum,
                                               const float* __restrict__ ssq,
                                               const float* __restrict__ g,
                                               const float* __restrict__ bb, float invN,
                                               float* __restrict__ out, int total4) {
    __shared__ float scs[64], shs[64];
    int tx = threadIdx.x;
    if (tx < 64) {
        float mu = ssum[tx] * invN;
        float var = ssq[tx] * invN - mu * mu;
        float s = g[tx] * rsqrtf(var + EPS);
        scs[tx] = s;
        shs[tx] = bb[tx] - mu * s;
    }
    __syncthreads();
    int t = blockIdx.x * blockDim.x + tx;
    if (t < total4) {
        float4 v = ((const float4*)In)[t];
        int j = (t * 4) & 63;
        v.x = v.x * scs[j + 0] + shs[j + 0];
        v.y = v.y * scs[j + 1] + shs[j + 1];
        v.z = v.z * scs[j + 2] + shs[j + 2];
        v.w = v.w * scs[j + 3] + shs[j + 3];
        ((float4*)out)[t] = v;
    }
}

extern "C" void kernel_launch(void* const* d_in, const int* in_sizes, int n_in,
                              void* d_out, int out_size, void* d_ws, size_t ws_size,
                              hipStream_t stream) {
    const float* x       = (const float*)d_in[0];
    const int*   ei      = (const int*)d_in[1];
    const float* bn_in_g = (const float*)d_in[2];
    const float* bn_in_b = (const float*)d_in[3];
    const float* Wp      = (const float*)d_in[4];
    const float* bp      = (const float*)d_in[5];
    const float* W1      = (const float*)d_in[6];
    const float* b1      = (const float*)d_in[7];
    const float* bn1_g   = (const float*)d_in[8];
    const float* bn1_b   = (const float*)d_in[9];
    const float* W2      = (const float*)d_in[10];
    const float* b2      = (const float*)d_in[11];
    const float* bn2_g   = (const float*)d_in[12];
    const float* bn2_b   = (const float*)d_in[13];

    int N = in_sizes[0] / 128;
    int E = in_sizes[1] / 2;
    const int* src = ei;
    const int* dst = ei + E;
    int Nh  = N >> 1;
    int NB  = (N + 255) >> 8;              // 256-node buckets (<=512)
    int NBP = (E + PCHUNK - 1) / PCHUNK;   // partition blocks
    int nbg = (N + 511) / 512;             // gemm1 blocks (512 thr)

    long long Npad = ((long long)N + 128) & ~127LL;
    int*   cur    = (int*)d_ws;            // 512
    float* stats  = (float*)(cur + 512);   // 512
    int2*  rowbe  = (int2*)(stats + 512);  // Npad int2
    float* dinv   = (float*)(rowbe + Npad);
    int*   rowmid = (int*)(dinv + Npad);   // Npad ints (segment split point)
    unsigned* packbuf = (unsigned*)(rowmid + Npad);            // NB*CAP
    int*   eidx   = (int*)(packbuf + (long long)NB * CAP);     // NB*CAP
    unsigned* Hq  = (unsigned*)(eidx + (long long)NB * CAP);   // Npad*32 (bf16 rows, 128 B)
    float* H      = (float*)d_out;         // N*64 intermediate + final out

    int nb = (N + 255) / 256;
    int gb = (N + 31) / 32;
    float invN = 1.0f / (float)N;

    k_init<<<1, 512, 0, stream>>>(cur, stats);
    // partition || colstats(x)
    k_A<<<NBP + 512, 256, 0, stream>>>(src, dst, cur, packbuf, E, NBP,
                                       x, stats, stats + 128, N);
    // CSR build (segmented) || gemm1
    k_B<<<NB + nbg, 512, 0, stream>>>(packbuf, cur, rowbe, rowmid, dinv, eidx, NB, N, Nh,
                                      x, stats, bn_in_g, bn_in_b, Wp, bp, H, invN);

    // conv1
    k_gemm_rows<false><<<nb, 256, 0, stream>>>(H, W1, dinv, nullptr, nullptr, nullptr,
                                               nullptr, invN, Hq, N);
    k_gather_finish<<<gb, 256, 0, stream>>>((const uint4*)Hq, rowbe, rowmid, eidx, dinv,
                                            b1, H, stats + 256, stats + 320, N);

    // conv2 (BN1 scale/shift computed inline from stats)
    k_gemm_rows<true><<<nb, 256, 0, stream>>>(H, W2, dinv, stats + 256, stats + 320,
                                              bn1_g, bn1_b, invN, Hq, N);
    k_gather_finish<<<gb, 256, 0, stream>>>((const uint4*)Hq, rowbe, rowmid, eidx, dinv,
                                            b2, H, stats + 384, stats + 448, N);

    // final BN (scale/shift inline)
    k_final<<<(N * 16 + 255) / 256, 256, 0, stream>>>(H, stats + 384, stats + 448,
                                                      bn2_g, bn2_b, invN, H, N * 16);
}

// Round 6
// 507.532 us; speedup vs baseline: 1.0122x; 1.0122x over previous
//
#include <hip/hip_runtime.h>
#include <hip/hip_bf16.h>

#define EPS 1e-5f
#define CAP 6144     // slots per 256-node bucket (expected 4092 edges, 32-sigma slack)
#define PCHUNK 4096

// decode 8 int8 lanes from uint2 and accumulate with scale
__device__ __forceinline__ void acc_q(float* acc, uint2 v, float s) {
    acc[0] += s * (float)((int)(v.x << 24) >> 24);
    acc[1] += s * (float)((int)(v.x << 16) >> 24);
    acc[2] += s * (float)((int)(v.x << 8) >> 24);
    acc[3] += s * (float)((int)v.x >> 24);
    acc[4] += s * (float)((int)(v.y << 24) >> 24);
    acc[5] += s * (float)((int)(v.y << 16) >> 24);
    acc[6] += s * (float)((int)(v.y << 8) >> 24);
    acc[7] += s * (float)((int)v.y >> 24);
}

// ---------------- init: bucket cursors + zero stats ----------------
__global__ void k_init(int* __restrict__ cur, float* __restrict__ stats) {
    int t = threadIdx.x;  // 512
    stats[t] = 0.0f;
    cur[t] = t * CAP;
}

// ------- fused: blocks [0,NBP) fixed-cap partition; blocks [NBP,NBP+512) colstats x -------
__global__ __launch_bounds__(256) void k_A(
    const int* __restrict__ src, const int* __restrict__ dst,
    int* __restrict__ cur, unsigned* __restrict__ packbuf, int E, int NBP,
    const float* __restrict__ x, float* __restrict__ xsum, float* __restrict__ xsq, int N) {
    __shared__ int h[512], delta[512], wsc[4];
    __shared__ unsigned buf[PCHUNK];
    __shared__ int addr[PCHUNK];
    int tx = threadIdx.x;
    if ((int)blockIdx.x < NBP) {
        int e0 = blockIdx.x * PCHUNK;
        int e1 = min(e0 + PCHUNK, E);
        int csize = e1 - e0;
        h[tx] = 0; h[tx + 256] = 0;
        __syncthreads();
        for (int e = e0 + tx; e < e1; e += 256)
            atomicAdd(&h[dst[e] >> 8], 1);
        __syncthreads();
        int b0 = tx * 2;
        int c0 = h[b0], c1 = h[b0 + 1];
        int tsum = c0 + c1;
        int lane = tx & 63, wid = tx >> 6;
        int v = tsum;
#pragma unroll
        for (int off = 1; off < 64; off <<= 1) {
            int u = __shfl_up(v, off);
            if (lane >= off) v += u;
        }
        if (lane == 63) wsc[wid] = v;
        __syncthreads();
        int wbase = 0;
        for (int w = 0; w < wid; w++) wbase += wsc[w];
        int excl0 = wbase + v - tsum;
        int excl1 = excl0 + c0;
        if (c0 > 0) delta[b0] = atomicAdd(&cur[b0], c0) - excl0;
        if (c1 > 0) delta[b0 + 1] = atomicAdd(&cur[b0 + 1], c1) - excl1;
        __syncthreads();
        h[b0] = excl0; h[b0 + 1] = excl1;
        __syncthreads();
        for (int e = e0 + tx; e < e1; e += 256) {
            int d = dst[e];
            int b = d >> 8;
            int rank = atomicAdd(&h[b], 1);
            buf[rank] = ((unsigned)src[e] << 8) | (unsigned)(d & 255);
            addr[rank] = delta[b];
        }
        __syncthreads();
        for (int i = tx; i < csize; i += 256)
            packbuf[addr[i] + i] = buf[i];
    } else {
        float* ls = (float*)buf;
        float* lq = ls + 256;
        int b2 = blockIdx.x - NBP;  // 0..511
        int col = tx & 127, half = tx >> 7;
        float s = 0.f, q = 0.f;
        for (int r = b2 * 2 + half; r < N; r += 1024) {
            float v = x[(long long)r * 128 + col];
            s += v; q += v * v;
        }
        ls[tx] = s; lq[tx] = q;
        __syncthreads();
        if (half == 0) {
            s = ls[tx] + ls[tx + 128];
            q = lq[tx] + lq[tx + 128];
            atomicAdd(&xsum[col], s);
            atomicAdd(&xsq[col], q);
        }
    }
}

// ------- fused: blocks [0,NB) CSR build (src-half segmented); blocks [NB,..) gemm1 -------
__global__ __launch_bounds__(512) void k_B(
    const unsigned* __restrict__ packbuf, const int* __restrict__ cur,
    int2* __restrict__ rowbe, int* __restrict__ rowmid, float* __restrict__ dinv,
    int* __restrict__ eidx, int NB, int N, int Nh,
    const float* __restrict__ x, const float* __restrict__ stats,
    const float* __restrict__ g, const float* __restrict__ bbn,
    const float* __restrict__ Wp, const float* __restrict__ bp,
    float* __restrict__ H, float invN) {
    __shared__ int cnt[512], loff[512], wsum[8];
    int tx = threadIdx.x;  // 512
    if ((int)blockIdx.x < NB) {
        int b = blockIdx.x;
        int base = b * CAP;
        int end = cur[b];
        cnt[tx] = 0;
        __syncthreads();
        for (int e = base + tx; e < end; e += 512) {
            unsigned pk = packbuf[e];
            int key = (((int)pk & 255) << 1) | (int)((pk >> 8) >= (unsigned)Nh);
            atomicAdd(&cnt[key], 1);
        }
        __syncthreads();
        int c = cnt[tx];
        int lane = tx & 63, wid = tx >> 6;
        int v = c;
#pragma unroll
        for (int off = 1; off < 64; off <<= 1) {
            int u = __shfl_up(v, off);
            if (lane >= off) v += u;
        }
        if (lane == 63) wsum[wid] = v;
        __syncthreads();
        int wbase = 0;
        for (int w = 0; w < wid; w++) wbase += wsum[w];
        int excl = wbase + v - c;
        loff[tx] = excl;
        __syncthreads();
        if (tx < 256) {
            int node = b * 256 + tx;
            if (node < N) {
                int beg = base + loff[2 * tx];
                int mid = base + loff[2 * tx + 1];
                int e2 = mid + cnt[2 * tx + 1];
                rowbe[node] = make_int2(beg, e2);
                rowmid[node] = mid;
                int deg = cnt[2 * tx] + cnt[2 * tx + 1];
                dinv[node] = rsqrtf(1.0f + (float)deg);
            }
        }
        __syncthreads();
        for (int e = base + tx; e < end; e += 512) {
            unsigned pk = packbuf[e];
            int key = (((int)pk & 255) << 1) | (int)((pk >> 8) >= (unsigned)Nh);
            int pos = atomicAdd(&loff[key], 1);
            eidx[base + pos] = (int)(pk >> 8);
        }
    } else {
        float* sc = (float*)cnt;   // 128
        float* sh = (float*)loff;  // 128
        if (tx < 128) {
            float mu = stats[tx] * invN;
            float var = stats[128 + tx] * invN - mu * mu;
            float s = g[tx] * rsqrtf(var + EPS);
            sc[tx] = s;
            sh[tx] = bbn[tx] - mu * s;
        }
        __syncthreads();
        int r = ((int)blockIdx.x - NB) * 512 + tx;
        if (r >= N) return;
        float acc[64];
#pragma unroll
        for (int j = 0; j < 64; j++) acc[j] = 0.f;
        const float4* x4 = (const float4*)(x + (long long)r * 128);
        for (int c4 = 0; c4 < 32; c4++) {
            float4 xv = x4[c4];
            int cb = c4 * 4;
            xv.x = xv.x * sc[cb + 0] + sh[cb + 0];
            xv.y = xv.y * sc[cb + 1] + sh[cb + 1];
            xv.z = xv.z * sc[cb + 2] + sh[cb + 2];
            xv.w = xv.w * sc[cb + 3] + sh[cb + 3];
#pragma unroll
            for (int q = 0; q < 4; q++) {
                float xs = (q == 0) ? xv.x : (q == 1) ? xv.y : (q == 2) ? xv.z : xv.w;
                const float* wrow = Wp + (c4 * 4 + q) * 64;
#pragma unroll
                for (int j = 0; j < 64; j++) acc[j] += xs * wrow[j];
            }
        }
        float4* out4 = (float4*)(H + (long long)r * 64);
#pragma unroll
        for (int i = 0; i < 16; i++) {
            float4 vv;
            vv.x = fmaxf(acc[4 * i + 0] + bp[4 * i + 0], 0.f);
            vv.y = fmaxf(acc[4 * i + 1] + bp[4 * i + 1], 0.f);
            vv.z = fmaxf(acc[4 * i + 2] + bp[4 * i + 2], 0.f);
            vv.w = fmaxf(acc[4 * i + 3] + bp[4 * i + 3], 0.f);
            out4[i] = vv;
        }
    }
}

// ------- gemm_scale: hs = (optional BN+relu(In)) @ W * dinv[row] -> int8 rows + bf16 scale -------
template <bool BNRELU>
__global__ __launch_bounds__(256) void k_gemm_scale(
    const float* __restrict__ In, const float* __restrict__ W,
    const float* __restrict__ dinv, const float* __restrict__ ssum,
    const float* __restrict__ ssq, const float* __restrict__ g,
    const float* __restrict__ bb, float invN, unsigned* __restrict__ Bq,
    float* __restrict__ S, int N) {
    __shared__ float scs[64], shs[64];
    int tx = threadIdx.x;
    if (BNRELU) {
        if (tx < 64) {
            float mu = ssum[tx] * invN;
            float var = ssq[tx] * invN - mu * mu;
            float s = g[tx] * rsqrtf(var + EPS);
            scs[tx] = s;
            shs[tx] = bb[tx] - mu * s;
        }
        __syncthreads();
    }
    int r = blockIdx.x * blockDim.x + tx;
    if (r >= N) return;
    float acc[64];
#pragma unroll
    for (int j = 0; j < 64; j++) acc[j] = 0.f;
    const float4* in4 = (const float4*)(In + (long long)r * 64);
    for (int c4 = 0; c4 < 16; c4++) {
        float4 xv = in4[c4];
        if (BNRELU) {
            int cb = c4 * 4;
            xv.x = fmaxf(xv.x * scs[cb + 0] + shs[cb + 0], 0.f);
            xv.y = fmaxf(xv.y * scs[cb + 1] + shs[cb + 1], 0.f);
            xv.z = fmaxf(xv.z * scs[cb + 2] + shs[cb + 2], 0.f);
            xv.w = fmaxf(xv.w * scs[cb + 3] + shs[cb + 3], 0.f);
        }
#pragma unroll
        for (int q = 0; q < 4; q++) {
            float xs = (q == 0) ? xv.x : (q == 1) ? xv.y : (q == 2) ? xv.z : xv.w;
            const float* wrow = W + (c4 * 4 + q) * 64;
#pragma unroll
            for (int j = 0; j < 64; j++) acc[j] += xs * wrow[j];
        }
    }
    float dv = dinv[r];
    float vmax = 0.f;
#pragma unroll
    for (int j = 0; j < 64; j++) {
        acc[j] *= dv;
        vmax = fmaxf(vmax, fabsf(acc[j]));
    }
    // round scale to a bf16-representable f32 so the packed 15-bit scale dequants exactly
    float sf = vmax * (1.0f / 127.0f);
    unsigned u = __float_as_uint(sf);
    unsigned ub = (u + 0x7fffu + ((u >> 16) & 1u)) & 0xffff0000u;
    float sbf = __uint_as_float(ub);
    S[r] = sbf;
    float inv = (vmax > 0.f) ? (1.0f / sbf) : 0.f;
    uint4* b4 = (uint4*)(Bq + (long long)r * 16);
#pragma unroll
    for (int i = 0; i < 4; i++) {
        unsigned w[4];
#pragma unroll
        for (int k2 = 0; k2 < 4; k2++) {
            int bsx = i * 16 + k2 * 4;
            int q0 = max(-127, min(127, (int)rintf(acc[bsx + 0] * inv)));
            int q1 = max(-127, min(127, (int)rintf(acc[bsx + 1] * inv)));
            int q2 = max(-127, min(127, (int)rintf(acc[bsx + 2] * inv)));
            int q3 = max(-127, min(127, (int)rintf(acc[bsx + 3] * inv)));
            w[k2] = ((unsigned)q0 & 255u) | (((unsigned)q1 & 255u) << 8) |
                    (((unsigned)q2 & 255u) << 16) | (((unsigned)q3 & 255u) << 24);
        }
        b4[i] = make_uint4(w[0], w[1], w[2], w[3]);
    }
}

// ------- pack: eidx2[k] = (bf15(S[src]) << 17) | src  (per conv) -------
__global__ __launch_bounds__(256) void k_pack(
    const int* __restrict__ eidx, const int* __restrict__ cur,
    const float* __restrict__ S, unsigned* __restrict__ eidx2) {
    int b = blockIdx.x;
    int base = b * CAP;
    int end = cur[b];
    for (int e = base + threadIdx.x; e < end; e += 256) {
        unsigned w = (unsigned)eidx[e];
        float s = S[w];                      // bf16-representable, positive
        unsigned bits15 = __float_as_uint(s) >> 16;  // 15 bits (sign 0)
        eidx2[e] = (bits15 << 17) | w;
    }
}

// ------- gather+finish: out[d] = dinv[d]*(hs[d] + sum_nbr hs[s]) + b; stats -------
// 8 lanes per node (lane owns uint2 = 8 int8 feats => 64 B/row = ONE sector per edge).
// Row scale rides in the upper 15 bits of the packed edge word — no side-table loads.
// MLP-8 chunks with idx prefetch; src-half segmented order retained.
__global__ __launch_bounds__(256) void k_gather_finish(
    const uint2* __restrict__ Q, const unsigned* __restrict__ eidx2,
    const float* __restrict__ S,
    const int2* __restrict__ rowbe, const int* __restrict__ rowmid,
    const float* __restrict__ dinv, const float* __restrict__ bias,
    float* __restrict__ Out, float* __restrict__ ssum, float* __restrict__ ssq,
    int N) {
    int tx = threadIdx.x;
    int g = tx >> 3;   // node slot in block (32 per block)
    int l = tx & 7;    // feature octet
    int d = blockIdx.x * 32 + g;

    float s[8], q[8];
#pragma unroll
    for (int j = 0; j < 8; j++) { s[j] = 0.f; q[j] = 0.f; }

    if (d < N) {
        int2 be = rowbe[d];
        int mid = rowmid[d];
        uint2 v0 = Q[(long long)d * 8 + l];
        float sd = S[d];
        float dv = dinv[d];

        float acc[8];
#pragma unroll
        for (int j = 0; j < 8; j++) acc[j] = 0.f;

        for (int seg = 0; seg < 2; seg++) {
            int k  = seg ? mid : be.x;
            int ke = seg ? be.y : mid;
            if (k >= ke) continue;
            unsigned w_cur[8];
#pragma unroll
            for (int j = 0; j < 8; j++)
                w_cur[j] = (k + j < ke) ? eidx2[k + j] : (unsigned)N;  // scale bits 0

            while (k < ke) {
                uint2 bb[8];
#pragma unroll
                for (int j = 0; j < 8; j++)
                    bb[j] = Q[(long long)(w_cur[j] & 0x1ffffu) * 8 + l];
                int kn = k + 8;
                unsigned w_nxt[8];
#pragma unroll
                for (int j = 0; j < 8; j++)
                    w_nxt[j] = (kn + j < ke) ? eidx2[kn + j] : (unsigned)N;
#pragma unroll
                for (int j = 0; j < 8; j++) {
                    float sv = __uint_as_float((w_cur[j] >> 17) << 16);
                    acc_q(acc, bb[j], sv);
                }
#pragma unroll
                for (int j = 0; j < 8; j++) w_cur[j] = w_nxt[j];
                k = kn;
            }
        }
        // self term
        acc_q(acc, v0, sd);

        float4 o0, o1;
#pragma unroll
        for (int j = 0; j < 8; j++) {
            float v = acc[j] * dv + bias[8 * l + j];
            ((j < 4) ? (&o0.x)[j] : (&o1.x)[j - 4]) = v;
            s[j] += v; q[j] += v * v;
        }
        float4* outp = (float4*)(Out + (long long)d * 64 + 8 * l);
        outp[0] = o0;
        outp[1] = o1;
    }

#pragma unroll
    for (int m = 8; m <= 32; m <<= 1) {
#pragma unroll
        for (int j = 0; j < 8; j++) {
            s[j] += __shfl_xor(s[j], m, 64);
            q[j] += __shfl_xor(q[j], m, 64);
        }
    }
    __shared__ float ws_s[4][64], ws_q[4][64];
    int wv = tx >> 6, ln = tx & 63;
    if (ln < 8) {
#pragma unroll
        for (int j = 0; j < 8; j++) {
            ws_s[wv][ln * 8 + j] = s[j];
            ws_q[wv][ln * 8 + j] = q[j];
        }
    }
    __syncthreads();
    if (tx < 64) {
        float S2 = ws_s[0][tx] + ws_s[1][tx] + ws_s[2][tx] + ws_s[3][tx];
        float Q2 = ws_q[0][tx] + ws_q[1][tx] + ws_q[2][tx] + ws_q[3][tx];
        atomicAdd(&ssum[tx], S2);
        atomicAdd(&ssq[tx], Q2);
    }
}

// ---------------- final elementwise BN apply (stats inline, in-place safe) ----------------
__global__ __launch_bounds__(256) void k_final(const float* __restrict__ In,
                                               const float* __restrict__ ssum,
                                               const float* __restrict__ ssq,
                                               const float* __restrict__ g,
                                               const float* __restrict__ bb, float invN,
                                               float* __restrict__ out, int total4) {
    __shared__ float scs[64], shs[64];
    int tx = threadIdx.x;
    if (tx < 64) {
        float mu = ssum[tx] * invN;
        float var = ssq[tx] * invN - mu * mu;
        float s = g[tx] * rsqrtf(var + EPS);
        scs[tx] = s;
        shs[tx] = bb[tx] - mu * s;
    }
    __syncthreads();
    int t = blockIdx.x * blockDim.x + tx;
    if (t < total4) {
        float4 v = ((const float4*)In)[t];
        int j = (t * 4) & 63;
        v.x = v.x * scs[j + 0] + shs[j + 0];
        v.y = v.y * scs[j + 1] + shs[j + 1];
        v.z = v.z * scs[j + 2] + shs[j + 2];
        v.w = v.w * scs[j + 3] + shs[j + 3];
        ((float4*)out)[t] = v;
    }
}

extern "C" void kernel_launch(void* const* d_in, const int* in_sizes, int n_in,
                              void* d_out, int out_size, void* d_ws, size_t ws_size,
                              hipStream_t stream) {
    const float* x       = (const float*)d_in[0];
    const int*   ei      = (const int*)d_in[1];
    const float* bn_in_g = (const float*)d_in[2];
    const float* bn_in_b = (const float*)d_in[3];
    const float* Wp      = (const float*)d_in[4];
    const float* bp      = (const float*)d_in[5];
    const float* W1      = (const float*)d_in[6];
    const float* b1      = (const float*)d_in[7];
    const float* bn1_g   = (const float*)d_in[8];
    const float* bn1_b   = (const float*)d_in[9];
    const float* W2      = (const float*)d_in[10];
    const float* b2      = (const float*)d_in[11];
    const float* bn2_g   = (const float*)d_in[12];
    const float* bn2_b   = (const float*)d_in[13];

    int N = in_sizes[0] / 128;
    int E = in_sizes[1] / 2;
    const int* src = ei;
    const int* dst = ei + E;
    int Nh  = N >> 1;
    int NB  = (N + 255) >> 8;              // 256-node buckets (<=512)
    int NBP = (E + PCHUNK - 1) / PCHUNK;   // partition blocks
    int nbg = (N + 511) / 512;             // gemm1 blocks (512 thr)

    long long Npad = ((long long)N + 128) & ~127LL;
    int*   cur    = (int*)d_ws;            // 512
    float* stats  = (float*)(cur + 512);   // 512
    int2*  rowbe  = (int2*)(stats + 512);  // Npad int2
    float* dinv   = (float*)(rowbe + Npad);
    int*   rowmid = (int*)(dinv + Npad);   // Npad ints (segment split point)
    float* S      = (float*)(rowmid + Npad);                   // row scales (bf16-repr f32)
    unsigned* packbuf = (unsigned*)(S + Npad);                 // NB*CAP (reused as eidx2)
    int*   eidx   = (int*)(packbuf + (long long)NB * CAP);     // NB*CAP
    unsigned* Bq  = (unsigned*)(eidx + (long long)NB * CAP);   // Npad*16 (int8 rows, 64 B)
    float* H      = (float*)d_out;         // N*64 intermediate + final out
    unsigned* eidx2 = packbuf;             // dead after k_B, reused per conv

    int nb = (N + 255) / 256;
    int gb = (N + 31) / 32;
    float invN = 1.0f / (float)N;

    k_init<<<1, 512, 0, stream>>>(cur, stats);
    // partition || colstats(x)
    k_A<<<NBP + 512, 256, 0, stream>>>(src, dst, cur, packbuf, E, NBP,
                                       x, stats, stats + 128, N);
    // CSR build (segmented) || gemm1
    k_B<<<NB + nbg, 512, 0, stream>>>(packbuf, cur, rowbe, rowmid, dinv, eidx, NB, N, Nh,
                                      x, stats, bn_in_g, bn_in_b, Wp, bp, H, invN);

    // conv1: gemm+quant -> pack scales into edges -> gather
    k_gemm_scale<false><<<nb, 256, 0, stream>>>(H, W1, dinv, nullptr, nullptr, nullptr,
                                                nullptr, invN, Bq, S, N);
    k_pack<<<NB, 256, 0, stream>>>(eidx, cur, S, eidx2);
    k_gather_finish<<<gb, 256, 0, stream>>>((const uint2*)Bq, eidx2, S, rowbe, rowmid,
                                            dinv, b1, H, stats + 256, stats + 320, N);

    // conv2 (BN1 scale/shift inline from stats)
    k_gemm_scale<true><<<nb, 256, 0, stream>>>(H, W2, dinv, stats + 256, stats + 320,
                                               bn1_g, bn1_b, invN, Bq, S, N);
    k_pack<<<NB, 256, 0, stream>>>(eidx, cur, S, eidx2);
    k_gather_finish<<<gb, 256, 0, stream>>>((const uint2*)Bq, eidx2, S, rowbe, rowmid,
                                            dinv, b2, H, stats + 384, stats + 448, N);

    // final BN (scale/shift inline)
    k_final<<<(N * 16 + 255) / 256, 256, 0, stream>>>(H, stats + 384, stats + 448,
                                                      bn2_g, bn2_b, invN, H, N * 16);
}